// Round 3
// baseline (128.907 us; speedup 1.0000x reference)
//
#include <hip/hip_runtime.h>

// SSIM loss, wave-autonomous. B=32, H=W=512, win=11, out = 1 - mean(SSIM map).
// Each wave: 64-input-col strip (54 outputs) x 32-row band, vertical running
// moment sums in registers (add new row / subtract old row from L2), horizontal
// window via DPP wave-scan + bpermute shift. No LDS phases, no hot barriers.
// 5120 waves = 1280 blocks x 256 thr. Result via atomicAdd into d_out.

#define WW 512
#define OH 502
#define BANDROWS 32
#define INV_N (1.0f / 8064128.0f)   // 32*502*502

// x += dpp_shifted(x); bound_ctrl=1 -> shifted-in lanes contribute 0.
#define DPP_ADD(x, ctrl, rmask)                                            \
    x += __int_as_float(__builtin_amdgcn_update_dpp(                       \
        0, __float_as_int(x), (ctrl), (rmask), 0xf, true))

__device__ __forceinline__ float wave_iscan(float x) {
    DPP_ADD(x, 0x111, 0xf);   // row_shr:1
    DPP_ADD(x, 0x112, 0xf);   // row_shr:2
    DPP_ADD(x, 0x114, 0xf);   // row_shr:4
    DPP_ADD(x, 0x118, 0xf);   // row_shr:8
    DPP_ADD(x, 0x142, 0xa);   // row_bcast:15 -> rows 1,3
    DPP_ADD(x, 0x143, 0xc);   // row_bcast:31 -> rows 2,3
    return x;
}

__global__ __launch_bounds__(256, 5)
void ssim_main(const float* __restrict__ Pg, const float* __restrict__ Tg,
               float* __restrict__ outp) {
    const int tid  = threadIdx.x;
    const int lane = tid & 63;
    const int wv   = tid >> 6;
    const int Wid  = blockIdx.x * 4 + wv;      // 0..5119
    const int img   = Wid / 160;               // 10 strips * 16 bands
    const int rem   = Wid - img * 160;
    const int strip = rem >> 4;
    const int band  = rem & 15;

    const int col0 = (strip == 9) ? 448 : strip * 54;
    const int y0   = band * BANDROWS;
    const int y1   = min(OH, y0 + BANDROWS);   // band 15: 22 rows

    const int col    = col0 + lane;
    const bool active = (lane < 54) && (col >= strip * 54) && (col <= 501);

    const int base = img * (WW * WW) + col;

    // ---- prime vertical sums over input rows [y0, y0+10) ----
    float sp = 0.f, st = 0.f, sq = 0.f, sx = 0.f;
    {
        int idx = base + y0 * WW;
        #pragma unroll
        for (int r = 0; r < 10; ++r) {
            float p = Pg[idx], t = Tg[idx];
            sp += p; st += t;
            sq = fmaf(p, p, sq); sq = fmaf(t, t, sq);
            sx = fmaf(p, t, sx);
            idx += WW;
        }
    }

    int in = base + (y0 + 10) * WW;   // next row to add
    int io = base + y0 * WW;          // next row to subtract (L1/L2 hit)
    float pn = Pg[in], tn = Tg[in];
    float po = Pg[io], to = Tg[io];

    const float NP  = 121.f;
    const float cn  = 121.f / 120.f;
    const float C1n = 1e-4f * 121.f * 121.f;
    const float C2n = 9e-4f * 121.f * 121.f;

    float acc = 0.f;

    for (int y = y0; y < y1 - 1; ++y) {
        // add new row
        sp += pn; st += tn;
        sq = fmaf(pn, pn, sq); sq = fmaf(tn, tn, sq);
        sx = fmaf(pn, tn, sx);
        // prefetch next iteration's rows
        in += WW; io += WW;
        float pn2 = Pg[in], tn2 = Tg[in];
        float po2 = Pg[io], to2 = Tg[io];
        // horizontal: W[c] = S[c+10] - S[c] + v[c]
        float S0 = wave_iscan(sp), S1 = wave_iscan(st);
        float S2 = wave_iscan(sq), S3 = wave_iscan(sx);
        float W0 = __shfl(S0, lane + 10) - S0 + sp;
        float W1 = __shfl(S1, lane + 10) - S1 + st;
        float W2 = __shfl(S2, lane + 10) - S2 + sq;
        float W3 = __shfl(S3, lane + 10) - S3 + sx;
        if (active) {
            float m1 = W0 * W1;
            float q1 = fmaf(W0, W0, W1 * W1);
            float A1 = fmaf(2.f, m1, C1n);
            float B1 = q1 + C1n;
            float A2 = fmaf(2.f * cn, fmaf(NP, W3, -m1), C2n);
            float B2 = fmaf(cn, fmaf(NP, W2, -q1), C2n);
            acc = fmaf(A1 * A2, __builtin_amdgcn_rcpf(B1 * B2), acc);
        }
        // subtract old row
        sp -= po; st -= to;
        sq = fmaf(po, -po, sq); sq = fmaf(to, -to, sq);
        sx = fmaf(po, -to, sx);
        pn = pn2; tn = tn2; po = po2; to = to2;
    }
    // last row of band (no prefetch, no subtract)
    {
        sp += pn; st += tn;
        sq = fmaf(pn, pn, sq); sq = fmaf(tn, tn, sq);
        sx = fmaf(pn, tn, sx);
        float S0 = wave_iscan(sp), S1 = wave_iscan(st);
        float S2 = wave_iscan(sq), S3 = wave_iscan(sx);
        float W0 = __shfl(S0, lane + 10) - S0 + sp;
        float W1 = __shfl(S1, lane + 10) - S1 + st;
        float W2 = __shfl(S2, lane + 10) - S2 + sq;
        float W3 = __shfl(S3, lane + 10) - S3 + sx;
        if (active) {
            float m1 = W0 * W1;
            float q1 = fmaf(W0, W0, W1 * W1);
            float A1 = fmaf(2.f, m1, C1n);
            float B1 = q1 + C1n;
            float A2 = fmaf(2.f * cn, fmaf(NP, W3, -m1), C2n);
            float B2 = fmaf(cn, fmaf(NP, W2, -q1), C2n);
            acc = fmaf(A1 * A2, __builtin_amdgcn_rcpf(B1 * B2), acc);
        }
    }

    // ---- reduce: wave -> block -> one atomicAdd ----
    #pragma unroll
    for (int off = 32; off > 0; off >>= 1) acc += __shfl_down(acc, off);
    __shared__ float wred[4];
    if (lane == 0) wred[wv] = acc;
    __syncthreads();
    if (tid == 0) {
        float s = wred[0] + wred[1] + wred[2] + wred[3];
        float contrib = -s * INV_N;
        if (blockIdx.x == 0) contrib += 1.0f;
        atomicAdd(outp, contrib);
    }
}

extern "C" void kernel_launch(void* const* d_in, const int* in_sizes, int n_in,
                              void* d_out, int out_size, void* d_ws, size_t ws_size,
                              hipStream_t stream) {
    const float* pred = (const float*)d_in[0];
    const float* targ = (const float*)d_in[1];
    float* out = (float*)d_out;

    hipMemsetAsync(out, 0, sizeof(float), stream);
    ssim_main<<<dim3(1280), dim3(256), 0, stream>>>(pred, targ, out);
}

// Round 4
// 108.208 us; speedup vs baseline: 1.1913x; 1.1913x over previous
//
#include <hip/hip_runtime.h>

// SSIM loss, wave-autonomous + register ring buffer. B=32, H=W=512, win=11.
// Each wave: 128-col strip (118 outputs, 2 cols/lane via float2) x 44-row band.
// Vertical moment sums in registers; trailing 11 rows ring-buffered in VGPRs
// (no re-read). Horizontal 11-tap via pair DPP-scan + bpermute shifts.
// 1920 waves = 480 blocks x 256 thr. Result via atomicAdd into d_out.

#define WW 512
#define OH 502
#define BANDR 44
#define INV_N (1.0f / 8064128.0f)   // 32*502*502

#define DPP_ADD(x, ctrl, rmask)                                            \
    x += __int_as_float(__builtin_amdgcn_update_dpp(                       \
        0, __float_as_int(x), (ctrl), (rmask), 0xf, true))

__device__ __forceinline__ float wave_iscan(float x) {
    DPP_ADD(x, 0x111, 0xf);   // row_shr:1
    DPP_ADD(x, 0x112, 0xf);   // row_shr:2
    DPP_ADD(x, 0x114, 0xf);   // row_shr:4
    DPP_ADD(x, 0x118, 0xf);   // row_shr:8
    DPP_ADD(x, 0x142, 0xa);   // row_bcast:15 -> rows 1,3
    DPP_ADD(x, 0x143, 0xc);   // row_bcast:31 -> rows 2,3
    return x;
}

// 11-tap horizontal window sums for this lane's two columns (2l, 2l+1).
__device__ __forceinline__ float2 hwin(float v0, float v1, int lane) {
    float e = v0 + v1;            // pair sum
    float S = wave_iscan(e);      // inclusive scan over pairs
    float A4 = __shfl(S, lane + 4);
    float A5 = __shfl(S, lane + 5);
    float v5 = __shfl(v0, lane + 5);
    float W0 = A4 - S + e + v5;   // pairs l..l+4  + col 2l+10
    float W1 = A5 - S + v1;       // pairs l+1..l+5 + col 2l+1
    return make_float2(W0, W1);
}

__device__ __forceinline__ float ssim_term(float s0, float s1, float sq, float sx) {
    const float NP  = 121.f;
    const float cn  = 121.f / 120.f;
    const float C1n = 1e-4f * 121.f * 121.f;
    const float C2n = 9e-4f * 121.f * 121.f;
    float m1 = s0 * s1;
    float q1 = fmaf(s0, s0, s1 * s1);
    float A1 = fmaf(2.f, m1, C1n);
    float B1 = q1 + C1n;
    float A2 = fmaf(2.f * cn, fmaf(NP, sx, -m1), C2n);
    float B2 = fmaf(cn, fmaf(NP, sq, -q1), C2n);
    return A1 * A2 * __builtin_amdgcn_rcpf(B1 * B2);
}

__global__ __launch_bounds__(256)
void ssim_main(const float* __restrict__ Pg, const float* __restrict__ Tg,
               float* __restrict__ outp) {
    const int tid  = threadIdx.x;
    const int lane = tid & 63;
    const int wv   = tid >> 6;
    const int Wid  = blockIdx.x * 4 + wv;      // 0..1919
    const int img   = Wid / 60;                // 5 strips * 12 bands
    const int rem   = Wid - img * 60;
    const int strip = rem / 12;
    const int band  = rem - strip * 12;

    const int col0 = (strip == 4) ? 472 : strip * 118;
    const int outw = (strip == 4) ? 30 : 118;
    const int y0   = band * BANDR;
    const int rows = min(BANDR, OH - y0);      // band 11: 18

    const int cload = min(col0 + 2 * lane, 510);
    const bool ok   = lane < (outw >> 1);

    const float* Pb = Pg + img * (WW * WW);
    const float* Tb = Tg + img * (WW * WW);

    float2 prr[11], trr[11];
    float sp0 = 0.f, sp1 = 0.f, st0 = 0.f, st1 = 0.f;
    float sq0 = 0.f, sq1 = 0.f, sx0 = 0.f, sx1 = 0.f;

    // ---- prime: input rows y0..y0+9 into ring slots 0..9 ----
    #pragma unroll
    for (int r = 0; r < 10; ++r) {
        float2 p = *(const float2*)(Pb + (y0 + r) * WW + cload);
        float2 t = *(const float2*)(Tb + (y0 + r) * WW + cload);
        prr[r] = p; trr[r] = t;
        sp0 += p.x; sp1 += p.y; st0 += t.x; st1 += t.y;
        sq0 = fmaf(p.x, p.x, sq0); sq0 = fmaf(t.x, t.x, sq0);
        sq1 = fmaf(p.y, p.y, sq1); sq1 = fmaf(t.y, t.y, sq1);
        sx0 = fmaf(p.x, t.x, sx0); sx1 = fmaf(p.y, t.y, sx1);
    }
    float2 Pn = *(const float2*)(Pb + (y0 + 10) * WW + cload);
    float2 Tn = *(const float2*)(Tb + (y0 + 10) * WW + cload);

    float acc = 0.f;

    for (int yy = 0; yy < rows; yy += 11) {
        #pragma unroll
        for (int j = 0; j < 11; ++j) {
            if (yy + j < rows) {               // wave-uniform guard
                const int sn = (10 + j) % 11;  // static after unroll
                // consume prefetched new row
                prr[sn] = Pn; trr[sn] = Tn;
                sp0 += Pn.x; sp1 += Pn.y; st0 += Tn.x; st1 += Tn.y;
                sq0 = fmaf(Pn.x, Pn.x, sq0); sq0 = fmaf(Tn.x, Tn.x, sq0);
                sq1 = fmaf(Pn.y, Pn.y, sq1); sq1 = fmaf(Tn.y, Tn.y, sq1);
                sx0 = fmaf(Pn.x, Tn.x, sx0); sx1 = fmaf(Pn.y, Tn.y, sx1);
                // prefetch next row (clamped: always in-bounds)
                int nr = min(y0 + 11 + yy + j, 511);
                Pn = *(const float2*)(Pb + nr * WW + cload);
                Tn = *(const float2*)(Tb + nr * WW + cload);
                // horizontal windows + SSIM
                float2 w0 = hwin(sp0, sp1, lane);
                float2 w1 = hwin(st0, st1, lane);
                float2 w2 = hwin(sq0, sq1, lane);
                float2 w3 = hwin(sx0, sx1, lane);
                if (ok) {
                    acc += ssim_term(w0.x, w1.x, w2.x, w3.x);
                    acc += ssim_term(w0.y, w1.y, w2.y, w3.y);
                }
                // subtract oldest row (ring slot j)
                float2 po = prr[j], to = trr[j];
                sp0 -= po.x; sp1 -= po.y; st0 -= to.x; st1 -= to.y;
                sq0 = fmaf(po.x, -po.x, sq0); sq0 = fmaf(to.x, -to.x, sq0);
                sq1 = fmaf(po.y, -po.y, sq1); sq1 = fmaf(to.y, -to.y, sq1);
                sx0 = fmaf(po.x, -to.x, sx0); sx1 = fmaf(po.y, -to.y, sx1);
            }
        }
    }

    // ---- reduce: wave -> block -> one atomicAdd ----
    #pragma unroll
    for (int off = 32; off > 0; off >>= 1) acc += __shfl_down(acc, off);
    __shared__ float wred[4];
    if (lane == 0) wred[wv] = acc;
    __syncthreads();
    if (tid == 0) {
        float s = wred[0] + wred[1] + wred[2] + wred[3];
        float contrib = -s * INV_N;
        if (blockIdx.x == 0) contrib += 1.0f;
        atomicAdd(outp, contrib);
    }
}

extern "C" void kernel_launch(void* const* d_in, const int* in_sizes, int n_in,
                              void* d_out, int out_size, void* d_ws, size_t ws_size,
                              hipStream_t stream) {
    const float* pred = (const float*)d_in[0];
    const float* targ = (const float*)d_in[1];
    float* out = (float*)d_out;

    hipMemsetAsync(out, 0, sizeof(float), stream);
    ssim_main<<<dim3(480), dim3(256), 0, stream>>>(pred, targ, out);
}